// Round 2
// baseline (6994.727 us; speedup 1.0000x reference)
//
#include <hip/hip_runtime.h>
#include <stdint.h>
#include <stddef.h>

// BaselinePointerNetwork: B=1024, N=128, H=128, T=256
// Pipeline: e1 (emb,Q,K,V) -> e2 (attention -> att_emb) -> e3 (A1, P) -> decode (256 steps)
// ws regions (64MiB each): R0 = Q -> att -> A1, R1 = K -> P, R2 = V
// RNG: JAX threefry2x32, PARTITIONABLE semantics:
//   split (foldlike): key_t = (o0,o1) of tf(key,(0,t))
//   random_bits(32):  bits  = o0 ^ o1 of tf(key_t,(hi(i),lo(i))), i = b*128+n

#define NEGV (-1e9f)

__device__ __forceinline__ uint32_t rotl32(uint32_t v, int d) { return (v << d) | (v >> (32 - d)); }

// JAX threefry2x32 (20 rounds), key (k0,k1), counter (c0,c1)
__device__ __forceinline__ void threefry2x32(uint32_t k0, uint32_t k1, uint32_t c0, uint32_t c1,
                                             uint32_t& o0, uint32_t& o1) {
  uint32_t k2 = k0 ^ k1 ^ 0x1BD11BDAu;
  uint32_t x0 = c0 + k0, x1 = c1 + k1;
  x0 += x1; x1 = rotl32(x1, 13); x1 ^= x0;
  x0 += x1; x1 = rotl32(x1, 15); x1 ^= x0;
  x0 += x1; x1 = rotl32(x1, 26); x1 ^= x0;
  x0 += x1; x1 = rotl32(x1, 6);  x1 ^= x0;
  x0 += k1; x1 += k2 + 1u;
  x0 += x1; x1 = rotl32(x1, 17); x1 ^= x0;
  x0 += x1; x1 = rotl32(x1, 29); x1 ^= x0;
  x0 += x1; x1 = rotl32(x1, 16); x1 ^= x0;
  x0 += x1; x1 = rotl32(x1, 24); x1 ^= x0;
  x0 += k2; x1 += k0 + 2u;
  x0 += x1; x1 = rotl32(x1, 13); x1 ^= x0;
  x0 += x1; x1 = rotl32(x1, 15); x1 ^= x0;
  x0 += x1; x1 = rotl32(x1, 26); x1 ^= x0;
  x0 += x1; x1 = rotl32(x1, 6);  x1 ^= x0;
  x0 += k0; x1 += k1 + 3u;
  x0 += x1; x1 = rotl32(x1, 17); x1 ^= x0;
  x0 += x1; x1 = rotl32(x1, 29); x1 ^= x0;
  x0 += x1; x1 = rotl32(x1, 16); x1 ^= x0;
  x0 += x1; x1 = rotl32(x1, 24); x1 ^= x0;
  x0 += k1; x1 += k2 + 4u;
  x0 += x1; x1 = rotl32(x1, 13); x1 ^= x0;
  x0 += x1; x1 = rotl32(x1, 15); x1 ^= x0;
  x0 += x1; x1 = rotl32(x1, 26); x1 ^= x0;
  x0 += x1; x1 = rotl32(x1, 6);  x1 ^= x0;
  x0 += k2; x1 += k0 + 5u;
  o0 = x0; o1 = x1;
}

// out[n][h] = sum_k Alds[n][k]*W[k][h] + bias[h]; A in LDS [128][128] natural,
// W global staged through wst (16x128), out global [128][128].
__device__ void mm128(const float* Alds, float* wst,
                      const float* __restrict__ W, const float* __restrict__ bias,
                      float* outg, int t) {
  int wv = t >> 6, lane = t & 63;
  int j0 = lane * 2;
  float b0 = 0.f, b1 = 0.f;
  if (bias) { b0 = bias[j0]; b1 = bias[j0 + 1]; }
  int r0 = wv * 32;
  float acc0[4][8], acc1[4][8];
#pragma unroll
  for (int g = 0; g < 4; ++g)
#pragma unroll
    for (int r = 0; r < 8; ++r) { acc0[g][r] = b0; acc1[g][r] = b1; }
  for (int ks = 0; ks < 128; ks += 16) {
    __syncthreads();                       // protect wst from previous readers
    for (int i = t; i < 2048; i += 256) wst[i] = W[ks * 128 + i];
    __syncthreads();
#pragma unroll
    for (int k4 = 0; k4 < 16; k4 += 4) {
      float2 w[4];
#pragma unroll
      for (int kk = 0; kk < 4; ++kk) w[kk] = *(const float2*)&wst[(k4 + kk) * 128 + j0];
#pragma unroll
      for (int g = 0; g < 4; ++g)
#pragma unroll
        for (int r = 0; r < 8; ++r) {
          float4 a = *(const float4*)&Alds[(r0 + g * 8 + r) * 128 + ks + k4];
          acc0[g][r] = fmaf(a.x, w[0].x, acc0[g][r]); acc1[g][r] = fmaf(a.x, w[0].y, acc1[g][r]);
          acc0[g][r] = fmaf(a.y, w[1].x, acc0[g][r]); acc1[g][r] = fmaf(a.y, w[1].y, acc1[g][r]);
          acc0[g][r] = fmaf(a.z, w[2].x, acc0[g][r]); acc1[g][r] = fmaf(a.z, w[2].y, acc1[g][r]);
          acc0[g][r] = fmaf(a.w, w[3].x, acc0[g][r]); acc1[g][r] = fmaf(a.w, w[3].y, acc1[g][r]);
        }
    }
  }
#pragma unroll
  for (int g = 0; g < 4; ++g)
#pragma unroll
    for (int r = 0; r < 8; ++r) {
      int n = r0 + g * 8 + r;
      float2 o; o.x = acc0[g][r]; o.y = acc1[g][r];
      *(float2*)&outg[n * 128 + j0] = o;
    }
}

// ---- E1: emb -> Q, K, V (all natural [n][h]) ----
__global__ __launch_bounds__(256, 2) void pn_e1(
    const float* __restrict__ coords, const float* __restrict__ demands,
    const float* __restrict__ W_emb, const float* __restrict__ b_emb,
    const float* __restrict__ Wq, const float* __restrict__ bq,
    const float* __restrict__ Wk, const float* __restrict__ bk,
    const float* __restrict__ Wv, const float* __restrict__ bv,
    float* Qo, float* Ko, float* Vo) {
  __shared__ float emb[128 * 128];
  __shared__ float wst[16 * 128];
  __shared__ float nfx[128], nfy[128], nfd[128];
  int b = blockIdx.x, t = threadIdx.x;
  if (t < 128) {
    float2 c = ((const float2*)coords)[b * 128 + t];
    nfx[t] = c.x; nfy[t] = c.y; nfd[t] = demands[b * 128 + t];
  }
  __syncthreads();
  {
    int h = t >> 1, n0 = (t & 1) * 64;
    float w0 = W_emb[h], w1 = W_emb[128 + h], w2 = W_emb[256 + h], be = b_emb[h];
    for (int n = n0; n < n0 + 64; ++n) {
      float e = nfx[n] * w0;
      e = fmaf(nfy[n], w1, e);
      e = fmaf(nfd[n], w2, e);
      e = e + be;
      emb[n * 128 + h] = e;
    }
  }
  __syncthreads();
  mm128(emb, wst, Wq, bq, Qo + (size_t)b * 16384, t);
  mm128(emb, wst, Wk, bk, Ko + (size_t)b * 16384, t);
  mm128(emb, wst, Wv, bv, Vo + (size_t)b * 16384, t);
}

// ---- E2: att_emb = softmax(Q K^T / sqrt(H)) @ V  (att natural [n][h]) ----
// NOTE: atto aliases Qg (same ws region) -> no __restrict__ on them.
__global__ __launch_bounds__(256, 2) void pn_e2(
    const float* Qg, const float* __restrict__ Kg, const float* __restrict__ Vg, float* atto) {
  __shared__ float Ks[128 * 132];        // K[m][k], padded
  __shared__ float qb[4 * 512];          // per-wave 4 rows x 128 (q, then p)
  int b = blockIdx.x, t = threadIdx.x;
  int wv = t >> 6, lane = t & 63;
  const float sden = sqrtf(128.0f);
  for (int i = t; i < 16384; i += 256) {
    int m = i >> 7, k = i & 127;
    Ks[m * 132 + k] = Kg[(size_t)b * 16384 + i];
  }
  __syncthreads();
  const float* Vb = Vg + (size_t)b * 16384;
  for (int pass = 0; pass < 8; ++pass) {
    int nb = pass * 16 + wv * 4;
    for (int i = lane; i < 512; i += 64) qb[wv * 512 + i] = Qg[(size_t)b * 16384 + nb * 128 + i];
    __syncthreads();
    // s[r][m] = sum_h q[r][h]*K[m][h]
    float s0[4] = {0.f, 0.f, 0.f, 0.f}, s1[4] = {0.f, 0.f, 0.f, 0.f};
    for (int k = 0; k < 128; k += 4) {
      float4 ka = *(const float4*)&Ks[lane * 132 + k];
      float4 kb = *(const float4*)&Ks[(lane + 64) * 132 + k];
#pragma unroll
      for (int r = 0; r < 4; ++r) {
        float4 q = *(const float4*)&qb[wv * 512 + r * 128 + k];
        s0[r] = fmaf(q.x, ka.x, s0[r]); s0[r] = fmaf(q.y, ka.y, s0[r]);
        s0[r] = fmaf(q.z, ka.z, s0[r]); s0[r] = fmaf(q.w, ka.w, s0[r]);
        s1[r] = fmaf(q.x, kb.x, s1[r]); s1[r] = fmaf(q.y, kb.y, s1[r]);
        s1[r] = fmaf(q.z, kb.z, s1[r]); s1[r] = fmaf(q.w, kb.w, s1[r]);
      }
    }
    // softmax rows (over m spread across lanes x 2)
    float p0[4], p1[4];
#pragma unroll
    for (int r = 0; r < 4; ++r) {
      float a0 = s0[r] / sden, a1 = s1[r] / sden;
      float mx = fmaxf(a0, a1);
#pragma unroll
      for (int off = 1; off < 64; off <<= 1) mx = fmaxf(mx, __shfl_xor(mx, off));
      float e0 = expf(a0 - mx), e1 = expf(a1 - mx);
      float sm = e0 + e1;
#pragma unroll
      for (int off = 1; off < 64; off <<= 1) sm += __shfl_xor(sm, off);
      p0[r] = e0 / sm; p1[r] = e1 / sm;
    }
#pragma unroll
    for (int r = 0; r < 4; ++r) {
      qb[wv * 512 + r * 128 + lane] = p0[r];
      qb[wv * 512 + r * 128 + lane + 64] = p1[r];
    }
    __syncthreads();
    // att[n_r][h] = sum_m p[r][m] * V[m][h]
    float o0[4] = {0.f, 0.f, 0.f, 0.f}, o1[4] = {0.f, 0.f, 0.f, 0.f};
    for (int m4 = 0; m4 < 128; m4 += 4) {
      float4 p[4];
#pragma unroll
      for (int r = 0; r < 4; ++r) p[r] = *(const float4*)&qb[wv * 512 + r * 128 + m4];
#pragma unroll
      for (int mm = 0; mm < 4; ++mm) {
        float v0 = Vb[(m4 + mm) * 128 + lane];
        float v1 = Vb[(m4 + mm) * 128 + lane + 64];
#pragma unroll
        for (int r = 0; r < 4; ++r) {
          float pv = (mm == 0) ? p[r].x : (mm == 1) ? p[r].y : (mm == 2) ? p[r].z : p[r].w;
          o0[r] = fmaf(pv, v0, o0[r]);
          o1[r] = fmaf(pv, v1, o1[r]);
        }
      }
    }
#pragma unroll
    for (int r = 0; r < 4; ++r) {
      atto[(size_t)b * 16384 + (nb + r) * 128 + lane] = o0[r];
      atto[(size_t)b * 16384 + (nb + r) * 128 + lane + 64] = o1[r];
    }
    __syncthreads();
  }
}

// ---- E3: A1 = att@Wp1[:128] + bp1 ; P = att@Wp1[128:] ----
// attg is fully staged into LDS before any write; A1o may alias attg (same region).
__global__ __launch_bounds__(256, 2) void pn_e3(
    const float* attg, const float* __restrict__ Wp1,
    const float* __restrict__ bp1, float* A1o, float* Po) {
  __shared__ float att[128 * 128];
  __shared__ float wst[16 * 128];
  int b = blockIdx.x, t = threadIdx.x;
  for (int i = t; i < 16384; i += 256) att[i] = attg[(size_t)b * 16384 + i];
  __syncthreads();
  mm128(att, wst, Wp1, bp1, A1o + (size_t)b * 16384, t);
  mm128(att, wst, Wp1 + 16384, (const float*)0, Po + (size_t)b * 16384, t);
}

// ---- decode: 256 sequential steps per batch element ----
__global__ __launch_bounds__(256, 1) void pn_decode(
    const float* __restrict__ A1g, const float* __restrict__ Pg,
    const float* __restrict__ demands, const float* __restrict__ caps,
    const float* __restrict__ Wp2, const float* __restrict__ bp2, float* out) {
  __shared__ float A1[128 * 133];        // 68,096 B  (133: odd-ish stride, 2-way-only conflicts)
  __shared__ float Pt[128 * 129];        // 66,048 B  P transposed: Pt[h][n]
  __shared__ float c1[128], dem[128], wp2s[128], scv[128], gv[128];
  __shared__ unsigned char mka[128];
  __shared__ int acts[256];
  __shared__ uint32_t keyA[256], keyB[256];
  __shared__ unsigned long long vism[2]; // visited bitmask (depot bit never set)
  __shared__ unsigned long long bal[2];
  __shared__ float red[6];
  __shared__ int redi[2];
  __shared__ float st_rc, st_lps;
  __shared__ int st_at, st_done, st_vc;

  int b = blockIdx.x, t = threadIdx.x;
  // step keys: foldlike split -> key_t = (o0,o1) of tf((0,42),(0,t))
  { uint32_t o0, o1; threefry2x32(0u, 42u, 0u, (uint32_t)t, o0, o1); keyA[t] = o0; keyB[t] = o1; }
  for (int i = t; i < 16384; i += 256) {
    int n = i >> 7, h = i & 127;
    float v = A1g[(size_t)b * 16384 + i];
    A1[n * 133 + h] = v;
    Pt[h * 129 + n] = Pg[(size_t)b * 16384 + i];
  }
  if (t < 128) { dem[t] = demands[b * 128 + t]; wp2s[t] = Wp2[t]; }
  if (t < 2) vism[t] = 0ull;
  float capv = caps[b];
  if (t == 0) { st_rc = capv; st_at = 1; st_done = 0; st_vc = 0; st_lps = 0.f; }
  float bp2v = bp2[0];
  __syncthreads();

  for (int step = 0; step < 256; ++step) {
    // P0: fresh masked sum -> c1 (waves 0,1) | gumbel + mask + ballot (waves 2,3)
    if (t < 128) {
      unsigned long long v0 = vism[0], v1 = vism[1];
      float cnt = fmaxf((float)(128 - st_vc), 1.f);
      const float* pr = &Pt[t * 129];
      float acc = 0.f;
#pragma unroll 8
      for (int n = 0; n < 64; ++n)
        acc += ((v0 >> n) & 1ull) ? 0.f : pr[n];
#pragma unroll 8
      for (int n = 0; n < 64; ++n)
        acc += ((v1 >> n) & 1ull) ? 0.f : pr[n + 64];
      c1[t] = acc / cnt;
    } else {
      int n = t - 128;
      unsigned long long vw = (n < 64) ? vism[0] : vism[1];
      bool vb = (vw >> (n & 63)) & 1ull;
      bool mk;
      if (n == 0) mk = (st_at != 0);                      // depot: visited=0, dem=0
      else mk = vb || (dem[n] > st_rc);
      mka[n] = mk ? 1 : 0;
      unsigned long long blt = __ballot(mk ? 1 : 0);
      if ((t & 63) == 0) bal[(t - 128) >> 6] = blt;
      // partitionable random_bits(32): bits = o0 ^ o1, counter (0, b*128+n)
      uint32_t o0, o1;
      threefry2x32(keyA[step], keyB[step], 0u, (uint32_t)(b * 128 + n), o0, o1);
      uint32_t bits = o0 ^ o1;
      uint32_t mb = bits >> 9;
      float u = (mb == 0u) ? 1.17549435e-38f : (float)mb * 1.1920928955078125e-07f;
      gv[n] = -logf(-logf(u));
    }
    __syncthreads();

    // P1: scores sc[n] = relu(A1[n]+c1) . Wp2 + bp2   (2 threads per node)
    {
      int n = t >> 1, half = t & 1;
      const float* arow = &A1[n * 133 + half * 64];
      const float* crow = &c1[half * 64];
      const float* wrow = &wp2s[half * 64];
      float acc = 0.f;
#pragma unroll
      for (int i = 0; i < 64; ++i) {
        float x = arow[i] + crow[i];
        x = fmaxf(x, 0.f);
        acc = fmaf(x, wrow[i], acc);
      }
      float other = __shfl_xor(acc, 1);
      if (half == 0) scv[n] = (acc + other) + bp2v;
    }
    __syncthreads();

    // P2 (all threads, redundant): done / mask0 logic
    int done = st_done;
    int at = st_at;
    if (st_vc == 127 && at) done = 1;
    bool am = (bal[0] == ~0ull) && (bal[1] == ~0ull);
    if (am && at) done = 1;

    // P3: logits, argmax(gumbel+logit), max(logit)
    if (t < 128) {
      int n = t;
      bool mk = (n == 0) ? (at && !done) : (mka[n] != 0);
      float lg = mk ? NEGV : scv[n];
      scv[n] = lg;
      float v = gv[n] + lg;
      int idx = n;
#pragma unroll
      for (int off = 1; off < 64; off <<= 1) {
        float ov = __shfl_xor(v, off);
        int oi = __shfl_xor(idx, off);
        if (ov > v || (ov == v && oi < idx)) { v = ov; idx = oi; }
      }
      float mx = lg;
#pragma unroll
      for (int off = 1; off < 64; off <<= 1) mx = fmaxf(mx, __shfl_xor(mx, off));
      if ((t & 63) == 0) { int w = t >> 6; red[w] = mx; red[2 + w] = v; redi[w] = idx; }
    }
    __syncthreads();

    float M = fmaxf(red[0], red[1]);
    int act_n = (red[3] > red[2]) ? redi[1] : redi[0];
    if (t < 128) {
      float e = expf(scv[t] - M);
#pragma unroll
      for (int off = 1; off < 64; off <<= 1) e += __shfl_xor(e, off);
      if ((t & 63) == 0) red[4 + (t >> 6)] = e;
    }
    __syncthreads();

    // P4: select, accumulate, update state
    float S = red[4] + red[5];
    int a = done ? 0 : act_n;
    if (t == 0) {
      float sel = done ? 0.f : ((scv[act_n] - M) - logf(S));
      st_lps += sel;
      acts[step] = a;
      if (!done) {
        if (a == 0) { st_rc = capv; st_at = 1; }
        else {
          st_rc = st_rc - dem[a]; st_at = 0; st_vc = st_vc + 1;
          vism[a >> 6] |= (1ull << (a & 63));
        }
      }
      st_done = done;
    }
    __syncthreads();
  }

  out[(size_t)b * 256 + t] = (float)acts[t];
  if (t == 0) out[(size_t)1024 * 256 + b] = st_lps;
}

extern "C" void kernel_launch(void* const* d_in, const int* in_sizes, int n_in,
                              void* d_out, int out_size, void* d_ws, size_t ws_size,
                              hipStream_t stream) {
  (void)in_sizes; (void)n_in; (void)out_size; (void)ws_size;
  const float* coords  = (const float*)d_in[0];
  const float* demands = (const float*)d_in[1];
  const float* caps    = (const float*)d_in[2];
  const float* W_emb   = (const float*)d_in[3];
  const float* b_emb   = (const float*)d_in[4];
  const float* Wq      = (const float*)d_in[5];
  const float* bq      = (const float*)d_in[6];
  const float* Wk      = (const float*)d_in[7];
  const float* bk      = (const float*)d_in[8];
  const float* Wv      = (const float*)d_in[9];
  const float* bv      = (const float*)d_in[10];
  const float* Wp1     = (const float*)d_in[11];
  const float* bp1     = (const float*)d_in[12];
  const float* Wp2     = (const float*)d_in[13];
  const float* bp2     = (const float*)d_in[14];

  float* ws = (float*)d_ws;
  const size_t R = (size_t)1024 * 128 * 128;  // 16,777,216 floats = 64 MiB
  float* R0 = ws;           // Q -> att_emb -> A1
  float* R1 = ws + R;       // K -> P
  float* R2 = ws + 2 * R;   // V

  pn_e1<<<1024, 256, 0, stream>>>(coords, demands, W_emb, b_emb, Wq, bq, Wk, bk, Wv, bv, R0, R1, R2);
  pn_e2<<<1024, 256, 0, stream>>>(R0, R1, R2, R0);
  pn_e3<<<1024, 256, 0, stream>>>(R0, Wp1, bp1, R0, R1);
  pn_decode<<<1024, 256, 0, stream>>>(R0, R1, demands, caps, Wp2, bp2, (float*)d_out);
}

// Round 3
// 3918.968 us; speedup vs baseline: 1.7848x; 1.7848x over previous
//
#include <hip/hip_runtime.h>
#include <stdint.h>
#include <stddef.h>

// BaselinePointerNetwork: B=1024, N=128, H=128, T=256
// Pipeline: e1 (emb,Q,K,V) -> e2 (attention -> att_emb) -> e3 (A1, P) -> decode (256 steps)
// ws regions (64MiB each): R0 = Q -> att -> A1, R1 = K -> P, R2 = V
// RNG: JAX threefry2x32, PARTITIONABLE semantics:
//   split (foldlike): key_t = (o0,o1) of tf(key,(0,t))
//   random_bits(32):  bits  = o0 ^ o1 of tf(key_t,(hi(i),lo(i))), i = b*128+n

#define NEGV (-1e9f)

__device__ __forceinline__ uint32_t rotl32(uint32_t v, int d) { return (v << d) | (v >> (32 - d)); }

// JAX threefry2x32 (20 rounds), key (k0,k1), counter (c0,c1)
__device__ __forceinline__ void threefry2x32(uint32_t k0, uint32_t k1, uint32_t c0, uint32_t c1,
                                             uint32_t& o0, uint32_t& o1) {
  uint32_t k2 = k0 ^ k1 ^ 0x1BD11BDAu;
  uint32_t x0 = c0 + k0, x1 = c1 + k1;
  x0 += x1; x1 = rotl32(x1, 13); x1 ^= x0;
  x0 += x1; x1 = rotl32(x1, 15); x1 ^= x0;
  x0 += x1; x1 = rotl32(x1, 26); x1 ^= x0;
  x0 += x1; x1 = rotl32(x1, 6);  x1 ^= x0;
  x0 += k1; x1 += k2 + 1u;
  x0 += x1; x1 = rotl32(x1, 17); x1 ^= x0;
  x0 += x1; x1 = rotl32(x1, 29); x1 ^= x0;
  x0 += x1; x1 = rotl32(x1, 16); x1 ^= x0;
  x0 += x1; x1 = rotl32(x1, 24); x1 ^= x0;
  x0 += k2; x1 += k0 + 2u;
  x0 += x1; x1 = rotl32(x1, 13); x1 ^= x0;
  x0 += x1; x1 = rotl32(x1, 15); x1 ^= x0;
  x0 += x1; x1 = rotl32(x1, 26); x1 ^= x0;
  x0 += x1; x1 = rotl32(x1, 6);  x1 ^= x0;
  x0 += k0; x1 += k1 + 3u;
  x0 += x1; x1 = rotl32(x1, 17); x1 ^= x0;
  x0 += x1; x1 = rotl32(x1, 29); x1 ^= x0;
  x0 += x1; x1 = rotl32(x1, 16); x1 ^= x0;
  x0 += x1; x1 = rotl32(x1, 24); x1 ^= x0;
  x0 += k1; x1 += k2 + 4u;
  x0 += x1; x1 = rotl32(x1, 13); x1 ^= x0;
  x0 += x1; x1 = rotl32(x1, 15); x1 ^= x0;
  x0 += x1; x1 = rotl32(x1, 26); x1 ^= x0;
  x0 += x1; x1 = rotl32(x1, 6);  x1 ^= x0;
  x0 += k2; x1 += k0 + 5u;
  o0 = x0; o1 = x1;
}

__device__ __forceinline__ float gumbel_from(uint32_t kA, uint32_t kB, uint32_t idx) {
  uint32_t o0, o1;
  threefry2x32(kA, kB, 0u, idx, o0, o1);
  uint32_t bits = o0 ^ o1;                 // partitionable: xor of both output words
  uint32_t mb = bits >> 9;
  float u = (mb == 0u) ? 1.17549435e-38f : (float)mb * 1.1920928955078125e-07f;
  return -logf(-logf(u));
}

// out[n][h] = sum_k Alds[n][k]*W[k][h] + bias[h]; A in LDS [128][128] natural,
// W global staged through wst (16x128), out global [128][128].
__device__ void mm128(const float* Alds, float* wst,
                      const float* __restrict__ W, const float* __restrict__ bias,
                      float* outg, int t) {
  int wv = t >> 6, lane = t & 63;
  int j0 = lane * 2;
  float b0 = 0.f, b1 = 0.f;
  if (bias) { b0 = bias[j0]; b1 = bias[j0 + 1]; }
  int r0 = wv * 32;
  float acc0[4][8], acc1[4][8];
#pragma unroll
  for (int g = 0; g < 4; ++g)
#pragma unroll
    for (int r = 0; r < 8; ++r) { acc0[g][r] = b0; acc1[g][r] = b1; }
  for (int ks = 0; ks < 128; ks += 16) {
    __syncthreads();                       // protect wst from previous readers
    for (int i = t; i < 2048; i += 256) wst[i] = W[ks * 128 + i];
    __syncthreads();
#pragma unroll
    for (int k4 = 0; k4 < 16; k4 += 4) {
      float2 w[4];
#pragma unroll
      for (int kk = 0; kk < 4; ++kk) w[kk] = *(const float2*)&wst[(k4 + kk) * 128 + j0];
#pragma unroll
      for (int g = 0; g < 4; ++g)
#pragma unroll
        for (int r = 0; r < 8; ++r) {
          float4 a = *(const float4*)&Alds[(r0 + g * 8 + r) * 128 + ks + k4];
          acc0[g][r] = fmaf(a.x, w[0].x, acc0[g][r]); acc1[g][r] = fmaf(a.x, w[0].y, acc1[g][r]);
          acc0[g][r] = fmaf(a.y, w[1].x, acc0[g][r]); acc1[g][r] = fmaf(a.y, w[1].y, acc1[g][r]);
          acc0[g][r] = fmaf(a.z, w[2].x, acc0[g][r]); acc1[g][r] = fmaf(a.z, w[2].y, acc1[g][r]);
          acc0[g][r] = fmaf(a.w, w[3].x, acc0[g][r]); acc1[g][r] = fmaf(a.w, w[3].y, acc1[g][r]);
        }
    }
  }
#pragma unroll
  for (int g = 0; g < 4; ++g)
#pragma unroll
    for (int r = 0; r < 8; ++r) {
      int n = r0 + g * 8 + r;
      float2 o; o.x = acc0[g][r]; o.y = acc1[g][r];
      *(float2*)&outg[n * 128 + j0] = o;
    }
}

// ---- E1: emb -> Q, K, V (all natural [n][h]) ----
__global__ __launch_bounds__(256, 2) void pn_e1(
    const float* __restrict__ coords, const float* __restrict__ demands,
    const float* __restrict__ W_emb, const float* __restrict__ b_emb,
    const float* __restrict__ Wq, const float* __restrict__ bq,
    const float* __restrict__ Wk, const float* __restrict__ bk,
    const float* __restrict__ Wv, const float* __restrict__ bv,
    float* Qo, float* Ko, float* Vo) {
  __shared__ float emb[128 * 128];
  __shared__ float wst[16 * 128];
  __shared__ float nfx[128], nfy[128], nfd[128];
  int b = blockIdx.x, t = threadIdx.x;
  if (t < 128) {
    float2 c = ((const float2*)coords)[b * 128 + t];
    nfx[t] = c.x; nfy[t] = c.y; nfd[t] = demands[b * 128 + t];
  }
  __syncthreads();
  {
    int h = t >> 1, n0 = (t & 1) * 64;
    float w0 = W_emb[h], w1 = W_emb[128 + h], w2 = W_emb[256 + h], be = b_emb[h];
    for (int n = n0; n < n0 + 64; ++n) {
      float e = nfx[n] * w0;
      e = fmaf(nfy[n], w1, e);
      e = fmaf(nfd[n], w2, e);
      e = e + be;
      emb[n * 128 + h] = e;
    }
  }
  __syncthreads();
  mm128(emb, wst, Wq, bq, Qo + (size_t)b * 16384, t);
  mm128(emb, wst, Wk, bk, Ko + (size_t)b * 16384, t);
  mm128(emb, wst, Wv, bv, Vo + (size_t)b * 16384, t);
}

// ---- E2: att_emb = softmax(Q K^T / sqrt(H)) @ V  (att natural [n][h]) ----
// NOTE: atto aliases Qg (same ws region) -> no __restrict__ on them.
__global__ __launch_bounds__(256, 2) void pn_e2(
    const float* Qg, const float* __restrict__ Kg, const float* __restrict__ Vg, float* atto) {
  __shared__ float Ks[128 * 132];        // K[m][k], padded
  __shared__ float qb[4 * 512];          // per-wave 4 rows x 128 (q, then p)
  int b = blockIdx.x, t = threadIdx.x;
  int wv = t >> 6, lane = t & 63;
  const float sden = sqrtf(128.0f);
  for (int i = t; i < 16384; i += 256) {
    int m = i >> 7, k = i & 127;
    Ks[m * 132 + k] = Kg[(size_t)b * 16384 + i];
  }
  __syncthreads();
  const float* Vb = Vg + (size_t)b * 16384;
  for (int pass = 0; pass < 8; ++pass) {
    int nb = pass * 16 + wv * 4;
    for (int i = lane; i < 512; i += 64) qb[wv * 512 + i] = Qg[(size_t)b * 16384 + nb * 128 + i];
    __syncthreads();
    float s0[4] = {0.f, 0.f, 0.f, 0.f}, s1[4] = {0.f, 0.f, 0.f, 0.f};
    for (int k = 0; k < 128; k += 4) {
      float4 ka = *(const float4*)&Ks[lane * 132 + k];
      float4 kb = *(const float4*)&Ks[(lane + 64) * 132 + k];
#pragma unroll
      for (int r = 0; r < 4; ++r) {
        float4 q = *(const float4*)&qb[wv * 512 + r * 128 + k];
        s0[r] = fmaf(q.x, ka.x, s0[r]); s0[r] = fmaf(q.y, ka.y, s0[r]);
        s0[r] = fmaf(q.z, ka.z, s0[r]); s0[r] = fmaf(q.w, ka.w, s0[r]);
        s1[r] = fmaf(q.x, kb.x, s1[r]); s1[r] = fmaf(q.y, kb.y, s1[r]);
        s1[r] = fmaf(q.z, kb.z, s1[r]); s1[r] = fmaf(q.w, kb.w, s1[r]);
      }
    }
    float p0[4], p1[4];
#pragma unroll
    for (int r = 0; r < 4; ++r) {
      float a0 = s0[r] / sden, a1 = s1[r] / sden;
      float mx = fmaxf(a0, a1);
#pragma unroll
      for (int off = 1; off < 64; off <<= 1) mx = fmaxf(mx, __shfl_xor(mx, off));
      float e0 = expf(a0 - mx), e1 = expf(a1 - mx);
      float sm = e0 + e1;
#pragma unroll
      for (int off = 1; off < 64; off <<= 1) sm += __shfl_xor(sm, off);
      p0[r] = e0 / sm; p1[r] = e1 / sm;
    }
#pragma unroll
    for (int r = 0; r < 4; ++r) {
      qb[wv * 512 + r * 128 + lane] = p0[r];
      qb[wv * 512 + r * 128 + lane + 64] = p1[r];
    }
    __syncthreads();
    float o0[4] = {0.f, 0.f, 0.f, 0.f}, o1[4] = {0.f, 0.f, 0.f, 0.f};
    for (int m4 = 0; m4 < 128; m4 += 4) {
      float4 p[4];
#pragma unroll
      for (int r = 0; r < 4; ++r) p[r] = *(const float4*)&qb[wv * 512 + r * 128 + m4];
#pragma unroll
      for (int mm = 0; mm < 4; ++mm) {
        float v0 = Vb[(m4 + mm) * 128 + lane];
        float v1 = Vb[(m4 + mm) * 128 + lane + 64];
#pragma unroll
        for (int r = 0; r < 4; ++r) {
          float pv = (mm == 0) ? p[r].x : (mm == 1) ? p[r].y : (mm == 2) ? p[r].z : p[r].w;
          o0[r] = fmaf(pv, v0, o0[r]);
          o1[r] = fmaf(pv, v1, o1[r]);
        }
      }
    }
#pragma unroll
    for (int r = 0; r < 4; ++r) {
      atto[(size_t)b * 16384 + (nb + r) * 128 + lane] = o0[r];
      atto[(size_t)b * 16384 + (nb + r) * 128 + lane + 64] = o1[r];
    }
    __syncthreads();
  }
}

// ---- E3: A1 = att@Wp1[:128] + bp1 ; P = att@Wp1[128:] ----
// attg is fully staged into LDS before any write; A1o may alias attg (same region).
__global__ __launch_bounds__(256, 2) void pn_e3(
    const float* attg, const float* __restrict__ Wp1,
    const float* __restrict__ bp1, float* A1o, float* Po) {
  __shared__ float att[128 * 128];
  __shared__ float wst[16 * 128];
  int b = blockIdx.x, t = threadIdx.x;
  for (int i = t; i < 16384; i += 256) att[i] = attg[(size_t)b * 16384 + i];
  __syncthreads();
  mm128(att, wst, Wp1, bp1, A1o + (size_t)b * 16384, t);
  mm128(att, wst, Wp1 + 16384, (const float*)0, Po + (size_t)b * 16384, t);
}

// ---- decode: 256 sequential steps per batch element ----
// v3: A1 in registers (64 f/thread, 2 threads per node), P natural-layout LDS (64 KB),
//     3 barriers/step, wave0-only reduction, gumbel prefetch on waves 2-3.
__global__ __launch_bounds__(256, 2) void pn_decode(
    const float* __restrict__ A1g, const float* __restrict__ Pg,
    const float* __restrict__ demands, const float* __restrict__ caps,
    const float* __restrict__ Wp2, const float* __restrict__ bp2, float* out) {
  __shared__ float P[128 * 128];         // natural [n][h]; column reads are 2-way (free)
  __shared__ float c1[128], dem[128], wp2s[128], scv[128];
  __shared__ float gv[2][128];           // double-buffered gumbels
  __shared__ unsigned char mka[128];
  __shared__ int acts[256];
  __shared__ uint32_t keyA[256], keyB[256];
  __shared__ unsigned long long vism[2]; // visited bitmask (depot bit never set)
  __shared__ unsigned long long bal[2];
  __shared__ float st_rc, st_lps;
  __shared__ int st_at, st_done, st_vc;

  int b = blockIdx.x, t = threadIdx.x;
  int wave = t >> 6, lane = t & 63;
  // step keys: foldlike split -> key_t = (o0,o1) of tf((0,42),(0,t))
  { uint32_t o0, o1; threefry2x32(0u, 42u, 0u, (uint32_t)t, o0, o1); keyA[t] = o0; keyB[t] = o1; }
  for (int i = t; i < 16384; i += 256) P[i] = Pg[(size_t)b * 16384 + i];
  // A1 fragment in registers: thread t holds A1[n = t>>1][half*64 + i], half = t&1
  int nrow = t >> 1, half = t & 1;
  float a1r[64];
  {
    const float4* src = (const float4*)(A1g + (size_t)b * 16384 + nrow * 128 + half * 64);
#pragma unroll
    for (int j = 0; j < 16; ++j) {
      float4 v = src[j];
      a1r[4 * j] = v.x; a1r[4 * j + 1] = v.y; a1r[4 * j + 2] = v.z; a1r[4 * j + 3] = v.w;
    }
  }
  if (t < 128) { dem[t] = demands[b * 128 + t]; wp2s[t] = Wp2[t]; }
  if (t < 2) vism[t] = 0ull;
  float capv = caps[b];
  if (t == 0) { st_rc = capv; st_at = 1; st_done = 0; st_vc = 0; st_lps = 0.f; }
  float bp2v = bp2[0];
  __syncthreads();
  if (t >= 128) gv[0][t - 128] = gumbel_from(keyA[0], keyB[0], (uint32_t)(b * 128 + (t - 128)));
  __syncthreads();

  for (int step = 0; step < 256; ++step) {
    int p = step & 1;
    // P0: fresh masked column sum -> c1 (waves 0,1) | mask + ballot (waves 2,3)
    if (t < 128) {
      unsigned long long v0 = vism[0], v1 = vism[1];
      float cnt = fmaxf((float)(128 - st_vc), 1.f);
      float acc = 0.f;
#pragma unroll 8
      for (int n = 0; n < 64; ++n)
        acc += ((v0 >> n) & 1ull) ? 0.f : P[n * 128 + t];
#pragma unroll 8
      for (int n = 0; n < 64; ++n)
        acc += ((v1 >> n) & 1ull) ? 0.f : P[(n + 64) * 128 + t];
      c1[t] = acc / cnt;
    } else {
      int n = t - 128;
      unsigned long long vw = (n < 64) ? vism[0] : vism[1];
      bool vb = (vw >> (n & 63)) & 1ull;
      bool mk;
      if (n == 0) mk = (st_at != 0);                      // depot: visited=0, dem=0
      else mk = vb || (dem[n] > st_rc);
      mka[n] = mk ? 1 : 0;
      unsigned long long blt = __ballot(mk ? 1 : 0);
      if ((t & 63) == 0) bal[(t - 128) >> 6] = blt;
    }
    __syncthreads();

    // P1: sc[n] = relu(A1[n]+c1) . Wp2 + bp2   (2 threads per node, A1 in regs)
    {
      const float* crow = &c1[half * 64];
      const float* wrow = &wp2s[half * 64];
      float acc = 0.f;
#pragma unroll
      for (int i = 0; i < 64; ++i) {
        float x = a1r[i] + crow[i];
        x = fmaxf(x, 0.f);
        acc = fmaf(x, wrow[i], acc);
      }
      float other = __shfl_xor(acc, 1);
      if (half == 0) scv[nrow] = (acc + other) + bp2v;
    }
    __syncthreads();

    // P3: wave 0 does the full 128-node reduction + state update;
    //     waves 2,3 prefetch next step's gumbels.
    if (wave == 0) {
      int done = st_done;
      int at = st_at;
      if (st_vc == 127 && at) done = 1;
      bool am = (bal[0] == ~0ull) && (bal[1] == ~0ull);
      if (am && at) done = 1;
      int n0 = lane, n1 = lane + 64;
      bool mk0 = (n0 == 0) ? (at && !done) : (mka[n0] != 0);
      bool mk1 = (mka[n1] != 0);
      float sc0 = scv[n0], sc1 = scv[n1];
      float lg0 = mk0 ? NEGV : sc0;
      float lg1 = mk1 ? NEGV : sc1;
      float g0 = gv[p][n0], g1 = gv[p][n1];
      float v0g = g0 + lg0, v1g = g1 + lg1;
      float v; int idx;
      if (v1g > v0g) { v = v1g; idx = n1; } else { v = v0g; idx = n0; }
      float mx = fmaxf(lg0, lg1);
#pragma unroll
      for (int off = 1; off < 64; off <<= 1) {
        float ov = __shfl_xor(v, off);
        int oi = __shfl_xor(idx, off);
        if (ov > v || (ov == v && oi < idx)) { v = ov; idx = oi; }
        mx = fmaxf(mx, __shfl_xor(mx, off));
      }
      // softmax denom (order change vs ref affects lps only in last ulp)
      float e = expf(lg0 - mx) + expf(lg1 - mx);
#pragma unroll
      for (int off = 1; off < 64; off <<= 1) e += __shfl_xor(e, off);
      if (lane == 0) {
        int a = done ? 0 : idx;
        float sellg = scv[idx];            // selected action is unmasked
        float sel = done ? 0.f : ((sellg - mx) - logf(e));
        st_lps += sel;
        acts[step] = a;
        if (!done) {
          if (a == 0) { st_rc = capv; st_at = 1; }
          else {
            st_rc = st_rc - dem[a]; st_at = 0; st_vc = st_vc + 1;
            vism[a >> 6] |= (1ull << (a & 63));
          }
        }
        st_done = done;
      }
    } else if (wave >= 2 && step < 255) {
      int n = t - 128;
      gv[1 - p][n] = gumbel_from(keyA[step + 1], keyB[step + 1], (uint32_t)(b * 128 + n));
    }
    __syncthreads();
  }

  out[(size_t)b * 256 + t] = (float)acts[t];
  if (t == 0) out[(size_t)1024 * 256 + b] = st_lps;
}

extern "C" void kernel_launch(void* const* d_in, const int* in_sizes, int n_in,
                              void* d_out, int out_size, void* d_ws, size_t ws_size,
                              hipStream_t stream) {
  (void)in_sizes; (void)n_in; (void)out_size; (void)ws_size;
  const float* coords  = (const float*)d_in[0];
  const float* demands = (const float*)d_in[1];
  const float* caps    = (const float*)d_in[2];
  const float* W_emb   = (const float*)d_in[3];
  const float* b_emb   = (const float*)d_in[4];
  const float* Wq      = (const float*)d_in[5];
  const float* bq      = (const float*)d_in[6];
  const float* Wk      = (const float*)d_in[7];
  const float* bk      = (const float*)d_in[8];
  const float* Wv      = (const float*)d_in[9];
  const float* bv      = (const float*)d_in[10];
  const float* Wp1     = (const float*)d_in[11];
  const float* bp1     = (const float*)d_in[12];
  const float* Wp2     = (const float*)d_in[13];
  const float* bp2     = (const float*)d_in[14];

  float* ws = (float*)d_ws;
  const size_t R = (size_t)1024 * 128 * 128;  // 16,777,216 floats = 64 MiB
  float* R0 = ws;           // Q -> att_emb -> A1
  float* R1 = ws + R;       // K -> P
  float* R2 = ws + 2 * R;   // V

  pn_e1<<<1024, 256, 0, stream>>>(coords, demands, W_emb, b_emb, Wq, bq, Wk, bk, Wv, bv, R0, R1, R2);
  pn_e2<<<1024, 256, 0, stream>>>(R0, R1, R2, R0);
  pn_e3<<<1024, 256, 0, stream>>>(R0, Wp1, bp1, R0, R1);
  pn_decode<<<1024, 256, 0, stream>>>(R0, R1, demands, caps, Wp2, bp2, (float*)d_out);
}

// Round 4
// 2307.755 us; speedup vs baseline: 3.0310x; 1.6982x over previous
//
#include <hip/hip_runtime.h>
#include <stdint.h>
#include <stddef.h>

// BaselinePointerNetwork: B=1024, N=128, H=128, T=256
// Pipeline: e1 (emb,Q,K,V) -> e2 (attention -> att_emb) -> e3 (A1, P) -> decode
// ws regions (64MiB each): R0 = Q -> att -> A1, R1 = K -> P, R2 = V
// RNG: JAX threefry2x32, PARTITIONABLE semantics:
//   split (foldlike): key_t = (o0,o1) of tf(key,(0,t))
//   random_bits(32):  bits  = o0 ^ o1 of tf(key_t,(hi(i),lo(i))), i = b*128+n

#define NEGV (-1e9f)

__device__ __forceinline__ uint32_t rotl32(uint32_t v, int d) { return (v << d) | (v >> (32 - d)); }

__device__ __forceinline__ void threefry2x32(uint32_t k0, uint32_t k1, uint32_t c0, uint32_t c1,
                                             uint32_t& o0, uint32_t& o1) {
  uint32_t k2 = k0 ^ k1 ^ 0x1BD11BDAu;
  uint32_t x0 = c0 + k0, x1 = c1 + k1;
  x0 += x1; x1 = rotl32(x1, 13); x1 ^= x0;
  x0 += x1; x1 = rotl32(x1, 15); x1 ^= x0;
  x0 += x1; x1 = rotl32(x1, 26); x1 ^= x0;
  x0 += x1; x1 = rotl32(x1, 6);  x1 ^= x0;
  x0 += k1; x1 += k2 + 1u;
  x0 += x1; x1 = rotl32(x1, 17); x1 ^= x0;
  x0 += x1; x1 = rotl32(x1, 29); x1 ^= x0;
  x0 += x1; x1 = rotl32(x1, 16); x1 ^= x0;
  x0 += x1; x1 = rotl32(x1, 24); x1 ^= x0;
  x0 += k2; x1 += k0 + 2u;
  x0 += x1; x1 = rotl32(x1, 13); x1 ^= x0;
  x0 += x1; x1 = rotl32(x1, 15); x1 ^= x0;
  x0 += x1; x1 = rotl32(x1, 26); x1 ^= x0;
  x0 += x1; x1 = rotl32(x1, 6);  x1 ^= x0;
  x0 += k0; x1 += k1 + 3u;
  x0 += x1; x1 = rotl32(x1, 17); x1 ^= x0;
  x0 += x1; x1 = rotl32(x1, 29); x1 ^= x0;
  x0 += x1; x1 = rotl32(x1, 16); x1 ^= x0;
  x0 += x1; x1 = rotl32(x1, 24); x1 ^= x0;
  x0 += k1; x1 += k2 + 4u;
  x0 += x1; x1 = rotl32(x1, 13); x1 ^= x0;
  x0 += x1; x1 = rotl32(x1, 15); x1 ^= x0;
  x0 += x1; x1 = rotl32(x1, 26); x1 ^= x0;
  x0 += x1; x1 = rotl32(x1, 6);  x1 ^= x0;
  x0 += k2; x1 += k0 + 5u;
  o0 = x0; o1 = x1;
}

__device__ __forceinline__ float gumbel_from(uint32_t kA, uint32_t kB, uint32_t idx) {
  uint32_t o0, o1;
  threefry2x32(kA, kB, 0u, idx, o0, o1);
  uint32_t bits = o0 ^ o1;                 // partitionable: xor of both output words
  uint32_t mb = bits >> 9;
  float u = (mb == 0u) ? 1.17549435e-38f : (float)mb * 1.1920928955078125e-07f;
  return -logf(-logf(u));
}

// out[n][h] = sum_k Alds[n][k]*W[k][h] + bias[h]
__device__ void mm128(const float* Alds, float* wst,
                      const float* __restrict__ W, const float* __restrict__ bias,
                      float* outg, int t) {
  int wv = t >> 6, lane = t & 63;
  int j0 = lane * 2;
  float b0 = 0.f, b1 = 0.f;
  if (bias) { b0 = bias[j0]; b1 = bias[j0 + 1]; }
  int r0 = wv * 32;
  float acc0[4][8], acc1[4][8];
#pragma unroll
  for (int g = 0; g < 4; ++g)
#pragma unroll
    for (int r = 0; r < 8; ++r) { acc0[g][r] = b0; acc1[g][r] = b1; }
  for (int ks = 0; ks < 128; ks += 16) {
    __syncthreads();
    for (int i = t; i < 2048; i += 256) wst[i] = W[ks * 128 + i];
    __syncthreads();
#pragma unroll
    for (int k4 = 0; k4 < 16; k4 += 4) {
      float2 w[4];
#pragma unroll
      for (int kk = 0; kk < 4; ++kk) w[kk] = *(const float2*)&wst[(k4 + kk) * 128 + j0];
#pragma unroll
      for (int g = 0; g < 4; ++g)
#pragma unroll
        for (int r = 0; r < 8; ++r) {
          float4 a = *(const float4*)&Alds[(r0 + g * 8 + r) * 128 + ks + k4];
          acc0[g][r] = fmaf(a.x, w[0].x, acc0[g][r]); acc1[g][r] = fmaf(a.x, w[0].y, acc1[g][r]);
          acc0[g][r] = fmaf(a.y, w[1].x, acc0[g][r]); acc1[g][r] = fmaf(a.y, w[1].y, acc1[g][r]);
          acc0[g][r] = fmaf(a.z, w[2].x, acc0[g][r]); acc1[g][r] = fmaf(a.z, w[2].y, acc1[g][r]);
          acc0[g][r] = fmaf(a.w, w[3].x, acc0[g][r]); acc1[g][r] = fmaf(a.w, w[3].y, acc1[g][r]);
        }
    }
  }
#pragma unroll
  for (int g = 0; g < 4; ++g)
#pragma unroll
    for (int r = 0; r < 8; ++r) {
      int n = r0 + g * 8 + r;
      float2 o; o.x = acc0[g][r]; o.y = acc1[g][r];
      *(float2*)&outg[n * 128 + j0] = o;
    }
}

// ---- E1: emb -> Q, K, V ----
__global__ __launch_bounds__(256, 2) void pn_e1(
    const float* __restrict__ coords, const float* __restrict__ demands,
    const float* __restrict__ W_emb, const float* __restrict__ b_emb,
    const float* __restrict__ Wq, const float* __restrict__ bq,
    const float* __restrict__ Wk, const float* __restrict__ bk,
    const float* __restrict__ Wv, const float* __restrict__ bv,
    float* Qo, float* Ko, float* Vo) {
  __shared__ float emb[128 * 128];
  __shared__ float wst[16 * 128];
  __shared__ float nfx[128], nfy[128], nfd[128];
  int b = blockIdx.x, t = threadIdx.x;
  if (t < 128) {
    float2 c = ((const float2*)coords)[b * 128 + t];
    nfx[t] = c.x; nfy[t] = c.y; nfd[t] = demands[b * 128 + t];
  }
  __syncthreads();
  {
    int h = t >> 1, n0 = (t & 1) * 64;
    float w0 = W_emb[h], w1 = W_emb[128 + h], w2 = W_emb[256 + h], be = b_emb[h];
    for (int n = n0; n < n0 + 64; ++n) {
      float e = nfx[n] * w0;
      e = fmaf(nfy[n], w1, e);
      e = fmaf(nfd[n], w2, e);
      e = e + be;
      emb[n * 128 + h] = e;
    }
  }
  __syncthreads();
  mm128(emb, wst, Wq, bq, Qo + (size_t)b * 16384, t);
  mm128(emb, wst, Wk, bk, Ko + (size_t)b * 16384, t);
  mm128(emb, wst, Wv, bv, Vo + (size_t)b * 16384, t);
}

// ---- E2: att_emb = softmax(Q K^T / sqrt(H)) @ V ----
__global__ __launch_bounds__(256, 2) void pn_e2(
    const float* Qg, const float* __restrict__ Kg, const float* __restrict__ Vg, float* atto) {
  __shared__ float Ks[128 * 132];
  __shared__ float qb[4 * 512];
  int b = blockIdx.x, t = threadIdx.x;
  int wv = t >> 6, lane = t & 63;
  const float sden = sqrtf(128.0f);
  for (int i = t; i < 16384; i += 256) {
    int m = i >> 7, k = i & 127;
    Ks[m * 132 + k] = Kg[(size_t)b * 16384 + i];
  }
  __syncthreads();
  const float* Vb = Vg + (size_t)b * 16384;
  for (int pass = 0; pass < 8; ++pass) {
    int nb = pass * 16 + wv * 4;
    for (int i = lane; i < 512; i += 64) qb[wv * 512 + i] = Qg[(size_t)b * 16384 + nb * 128 + i];
    __syncthreads();
    float s0[4] = {0.f, 0.f, 0.f, 0.f}, s1[4] = {0.f, 0.f, 0.f, 0.f};
    for (int k = 0; k < 128; k += 4) {
      float4 ka = *(const float4*)&Ks[lane * 132 + k];
      float4 kb = *(const float4*)&Ks[(lane + 64) * 132 + k];
#pragma unroll
      for (int r = 0; r < 4; ++r) {
        float4 q = *(const float4*)&qb[wv * 512 + r * 128 + k];
        s0[r] = fmaf(q.x, ka.x, s0[r]); s0[r] = fmaf(q.y, ka.y, s0[r]);
        s0[r] = fmaf(q.z, ka.z, s0[r]); s0[r] = fmaf(q.w, ka.w, s0[r]);
        s1[r] = fmaf(q.x, kb.x, s1[r]); s1[r] = fmaf(q.y, kb.y, s1[r]);
        s1[r] = fmaf(q.z, kb.z, s1[r]); s1[r] = fmaf(q.w, kb.w, s1[r]);
      }
    }
    float p0[4], p1[4];
#pragma unroll
    for (int r = 0; r < 4; ++r) {
      float a0 = s0[r] / sden, a1 = s1[r] / sden;
      float mx = fmaxf(a0, a1);
#pragma unroll
      for (int off = 1; off < 64; off <<= 1) mx = fmaxf(mx, __shfl_xor(mx, off));
      float e0 = expf(a0 - mx), e1 = expf(a1 - mx);
      float sm = e0 + e1;
#pragma unroll
      for (int off = 1; off < 64; off <<= 1) sm += __shfl_xor(sm, off);
      p0[r] = e0 / sm; p1[r] = e1 / sm;
    }
#pragma unroll
    for (int r = 0; r < 4; ++r) {
      qb[wv * 512 + r * 128 + lane] = p0[r];
      qb[wv * 512 + r * 128 + lane + 64] = p1[r];
    }
    __syncthreads();
    float o0[4] = {0.f, 0.f, 0.f, 0.f}, o1[4] = {0.f, 0.f, 0.f, 0.f};
    for (int m4 = 0; m4 < 128; m4 += 4) {
      float4 p[4];
#pragma unroll
      for (int r = 0; r < 4; ++r) p[r] = *(const float4*)&qb[wv * 512 + r * 128 + m4];
#pragma unroll
      for (int mm = 0; mm < 4; ++mm) {
        float v0 = Vb[(m4 + mm) * 128 + lane];
        float v1 = Vb[(m4 + mm) * 128 + lane + 64];
#pragma unroll
        for (int r = 0; r < 4; ++r) {
          float pv = (mm == 0) ? p[r].x : (mm == 1) ? p[r].y : (mm == 2) ? p[r].z : p[r].w;
          o0[r] = fmaf(pv, v0, o0[r]);
          o1[r] = fmaf(pv, v1, o1[r]);
        }
      }
    }
#pragma unroll
    for (int r = 0; r < 4; ++r) {
      atto[(size_t)b * 16384 + (nb + r) * 128 + lane] = o0[r];
      atto[(size_t)b * 16384 + (nb + r) * 128 + lane + 64] = o1[r];
    }
    __syncthreads();
  }
}

// ---- E3: A1 = att@Wp1[:128] + bp1 ; P = att@Wp1[128:] ----
__global__ __launch_bounds__(256, 2) void pn_e3(
    const float* attg, const float* __restrict__ Wp1,
    const float* __restrict__ bp1, float* A1o, float* Po) {
  __shared__ float att[128 * 128];
  __shared__ float wst[16 * 128];
  int b = blockIdx.x, t = threadIdx.x;
  for (int i = t; i < 16384; i += 256) att[i] = attg[(size_t)b * 16384 + i];
  __syncthreads();
  mm128(att, wst, Wp1, bp1, A1o + (size_t)b * 16384, t);
  mm128(att, wst, Wp1 + 16384, (const float*)0, Po + (size_t)b * 16384, t);
}

// ---- decode v4: Pt transposed (b128 column sums), Wp2+A1 in regs,
//      per-wave replicated state, 2 barriers/step, early break on done. ----
__global__ __launch_bounds__(256, 2) void pn_decode(
    const float* __restrict__ A1g, const float* __restrict__ Pg,
    const float* __restrict__ demands, const float* __restrict__ caps,
    const float* __restrict__ Wp2, const float* __restrict__ bp2, float* out) {
  __shared__ __align__(16) float Pt[128 * 132];  // Pt[h*132+n], pad 4 -> 2-way banks on b128
  __shared__ __align__(16) float c1[128];
  __shared__ float scv[128];
  __shared__ float dem[128];
  __shared__ int acts[256];
  __shared__ uint32_t keyA[256], keyB[256];

  int b = blockIdx.x, t = threadIdx.x;
  int lane = t & 63;
  // step keys: foldlike split -> key_t = (o0,o1) of tf((0,42),(0,t))
  { uint32_t o0, o1; threefry2x32(0u, 42u, 0u, (uint32_t)t, o0, o1); keyA[t] = o0; keyB[t] = o1; }
  for (int i = t; i < 16384; i += 256) {
    int n = i >> 7, h = i & 127;
    Pt[h * 132 + n] = Pg[(size_t)b * 16384 + i];
  }
  // A1 fragment + Wp2 fragment in registers: thread t owns node nrow=t>>1, half=t&1
  int nrow = t >> 1, half = t & 1;
  float a1r[64], w2r[64];
  {
    const float4* asrc = (const float4*)(A1g + (size_t)b * 16384 + nrow * 128 + half * 64);
    const float4* wsrc = (const float4*)(Wp2 + half * 64);
#pragma unroll
    for (int j = 0; j < 16; ++j) {
      float4 v = asrc[j];
      a1r[4 * j] = v.x; a1r[4 * j + 1] = v.y; a1r[4 * j + 2] = v.z; a1r[4 * j + 3] = v.w;
      float4 w = wsrc[j];
      w2r[4 * j] = w.x; w2r[4 * j + 1] = w.y; w2r[4 * j + 2] = w.z; w2r[4 * j + 3] = w.w;
    }
  }
  if (t < 128) dem[t] = demands[b * 128 + t];
  acts[t] = 0;
  float capv = caps[b];
  float bp2v = bp2[0];
  float dem0 = demands[b * 128 + lane];        // n0 = lane
  float dem1 = demands[b * 128 + lane + 64];   // n1 = lane + 64
  // per-wave replicated state (uniform across lanes; identical FP ops in every wave)
  unsigned long long vism0 = 0ull, vism1 = 0ull;
  float rc = capv, lps = 0.f;
  int at = 1, done = 0, vc = 0;
  __syncthreads();

  for (int step = 0; step < 256; ++step) {
    // A: c1[h] = (fresh ascending-n masked sum of Pt row h) / cnt   (threads 0-127)
    if (t < 128) {
      float cnt = fmaxf((float)(128 - vc), 1.f);
      const float* pr = &Pt[t * 132];
      float acc = 0.f;
#pragma unroll
      for (int q = 0; q < 32; ++q) {
        float4 p = *(const float4*)&pr[q * 4];
        unsigned long long w = (q < 16) ? vism0 : vism1;
        int base = (q * 4) & 63;
        acc += ((w >> base) & 1ull) ? 0.f : p.x;
        acc += ((w >> (base + 1)) & 1ull) ? 0.f : p.y;
        acc += ((w >> (base + 2)) & 1ull) ? 0.f : p.z;
        acc += ((w >> (base + 3)) & 1ull) ? 0.f : p.w;
      }
      c1[t] = acc / cnt;
    }
    __syncthreads();

    // B: sc[n] = relu(A1[n]+c1).Wp2 + bp2  (2 threads/node; same op order as v3)
    {
      const float* crow = &c1[half * 64];
      float acc = 0.f;
#pragma unroll
      for (int q = 0; q < 16; ++q) {
        float4 c4 = *(const float4*)&crow[q * 4];
        float x;
        x = a1r[4 * q] + c4.x;     x = fmaxf(x, 0.f); acc = fmaf(x, w2r[4 * q], acc);
        x = a1r[4 * q + 1] + c4.y; x = fmaxf(x, 0.f); acc = fmaf(x, w2r[4 * q + 1], acc);
        x = a1r[4 * q + 2] + c4.z; x = fmaxf(x, 0.f); acc = fmaf(x, w2r[4 * q + 2], acc);
        x = a1r[4 * q + 3] + c4.w; x = fmaxf(x, 0.f); acc = fmaf(x, w2r[4 * q + 3], acc);
      }
      float other = __shfl_xor(acc, 1);
      if (half == 0) scv[nrow] = (acc + other) + bp2v;
    }
    __syncthreads();

    // C: every wave redundantly: gumbels, masks, reduction, state update
    {
      uint32_t kA = keyA[step], kB = keyB[step];
      float g0 = gumbel_from(kA, kB, (uint32_t)(b * 128 + lane));
      float g1 = gumbel_from(kA, kB, (uint32_t)(b * 128 + lane + 64));
      bool mk0 = (lane == 0) ? (at != 0)
                             : ((((vism0 >> lane) & 1ull) != 0ull) || (dem0 > rc));
      bool mk1 = (((vism1 >> lane) & 1ull) != 0ull) || (dem1 > rc);
      unsigned long long bl0 = __ballot(mk0 ? 1 : 0);
      unsigned long long bl1 = __ballot(mk1 ? 1 : 0);
      int d = done;
      if (vc == 127 && at) d = 1;
      bool am = (bl0 == ~0ull) && (bl1 == ~0ull);
      if (am && at) d = 1;
      if (lane == 0) mk0 = (at && !d);           // final depot mask
      float sc0 = scv[lane], sc1 = scv[lane + 64];
      float lg0 = mk0 ? NEGV : sc0;
      float lg1 = mk1 ? NEGV : sc1;
      float v0g = g0 + lg0, v1g = g1 + lg1;
      float v; int idx;
      if (v1g > v0g) { v = v1g; idx = lane + 64; } else { v = v0g; idx = lane; }
      float mx = fmaxf(lg0, lg1);
#pragma unroll
      for (int off = 1; off < 64; off <<= 1) {
        float ov = __shfl_xor(v, off);
        int oi = __shfl_xor(idx, off);
        if (ov > v || (ov == v && oi < idx)) { v = ov; idx = oi; }
        mx = fmaxf(mx, __shfl_xor(mx, off));
      }
      float e = expf(lg0 - mx) + expf(lg1 - mx);
#pragma unroll
      for (int off = 1; off < 64; off <<= 1) e += __shfl_xor(e, off);
      int a = d ? 0 : idx;
      float sellg = scv[idx];                     // uniform index -> broadcast
      float sel = d ? 0.f : ((sellg - mx) - logf(e));
      lps += sel;
      if (t == 0) acts[step] = a;
      if (!d) {
        if (a == 0) { rc = capv; at = 1; }
        else {
          rc = rc - dem[a];
          at = 0; vc = vc + 1;
          if (a < 64) vism0 |= (1ull << a); else vism1 |= (1ull << (a - 64));
        }
      }
      done = d;
    }
    if (done) break;                              // absorbing; acts pre-zeroed
    __syncthreads();                              // publish nothing, order A's c1 WAR vs C's scv reads
  }

  __syncthreads();
  out[(size_t)b * 256 + t] = (float)acts[t];
  if (t == 0) out[(size_t)1024 * 256 + b] = lps;
}

extern "C" void kernel_launch(void* const* d_in, const int* in_sizes, int n_in,
                              void* d_out, int out_size, void* d_ws, size_t ws_size,
                              hipStream_t stream) {
  (void)in_sizes; (void)n_in; (void)out_size; (void)ws_size;
  const float* coords  = (const float*)d_in[0];
  const float* demands = (const float*)d_in[1];
  const float* caps    = (const float*)d_in[2];
  const float* W_emb   = (const float*)d_in[3];
  const float* b_emb   = (const float*)d_in[4];
  const float* Wq      = (const float*)d_in[5];
  const float* bq      = (const float*)d_in[6];
  const float* Wk      = (const float*)d_in[7];
  const float* bk      = (const float*)d_in[8];
  const float* Wv      = (const float*)d_in[9];
  const float* bv      = (const float*)d_in[10];
  const float* Wp1     = (const float*)d_in[11];
  const float* bp1     = (const float*)d_in[12];
  const float* Wp2     = (const float*)d_in[13];
  const float* bp2     = (const float*)d_in[14];

  float* ws = (float*)d_ws;
  const size_t R = (size_t)1024 * 128 * 128;  // 64 MiB per region
  float* R0 = ws;           // Q -> att_emb -> A1
  float* R1 = ws + R;       // K -> P
  float* R2 = ws + 2 * R;   // V

  pn_e1<<<1024, 256, 0, stream>>>(coords, demands, W_emb, b_emb, Wq, bq, Wk, bk, Wv, bv, R0, R1, R2);
  pn_e2<<<1024, 256, 0, stream>>>(R0, R1, R2, R0);
  pn_e3<<<1024, 256, 0, stream>>>(R0, Wp1, bp1, R0, R1);
  pn_decode<<<1024, 256, 0, stream>>>(R0, R1, demands, caps, Wp2, bp2, (float*)d_out);
}